// Round 10
// baseline (746.919 us; speedup 1.0000x reference)
//
#include <hip/hip_runtime.h>
#include <cfloat>
#include <cmath>

#define F_IN 128
#define HID 512

typedef short bf16x8 __attribute__((ext_vector_type(8)));
typedef float f32x4 __attribute__((ext_vector_type(4)));

// ---- bf16 split helpers (RNE) ----
__device__ static inline void split_bf16(float v, short& hi, short& lo) {
    unsigned u = __float_as_uint(v);
    unsigned r = u + 0x7FFF + ((u >> 16) & 1);
    hi = (short)(r >> 16);
    float hf = __uint_as_float(((unsigned)(unsigned short)hi) << 16);
    float res = v - hf;
    unsigned u2 = __float_as_uint(res);
    unsigned r2 = u2 + 0x7FFF + ((u2 >> 16) & 1);
    lo = (short)(r2 >> 16);
}

// ---------------- small utility kernels ----------------

__global__ void zero_kernel(int* __restrict__ a, int n) {
    int i = blockIdx.x * blockDim.x + threadIdx.x;
    if (i < n) a[i] = 0;
}

__global__ void count_in_kernel(const int* __restrict__ dst, int* __restrict__ cnt, int E) {
    int e = blockIdx.x * blockDim.x + threadIdx.x;
    if (e < E) atomicAdd(&cnt[dst[e]], 1);
}

// single-block scan (exclusive prefix sum); also writes offs[n] = total
__global__ void scan_kernel(const int* __restrict__ cnt, int* __restrict__ offs, int n) {
    __shared__ int buf[1024];
    __shared__ int carry_s;
    if (threadIdx.x == 0) carry_s = 0;
    __syncthreads();
    for (int base = 0; base < n; base += 1024) {
        int i = base + threadIdx.x;
        int v = (i < n) ? cnt[i] : 0;
        buf[threadIdx.x] = v;
        __syncthreads();
        for (int s = 1; s < 1024; s <<= 1) {
            int t = (threadIdx.x >= s) ? buf[threadIdx.x - s] : 0;
            __syncthreads();
            buf[threadIdx.x] += t;
            __syncthreads();
        }
        int total = buf[1023];
        if (i < n) offs[i] = carry_s + buf[threadIdx.x] - v;
        __syncthreads();
        if (threadIdx.x == 0) carry_s += total;
        __syncthreads();
    }
    if (threadIdx.x == 0) offs[n] = carry_s;
}

// dis + graph-boundary starts, merged (both N-grids)
__global__ void dis_starts_kernel(const int* __restrict__ offs, float* __restrict__ dis,
                                  const int* __restrict__ batch, int* __restrict__ starts,
                                  int n, int G) {
    int i = blockIdx.x * blockDim.x + threadIdx.x;
    if (i >= n) return;
    dis[i] = rsqrtf((float)(offs[i + 1] - offs[i] + 1));  // +1 self-loop
    int b = batch[i];
    if (i == 0) {
        for (int g = 0; g <= b; g++) starts[g] = 0;
    } else {
        int bp = batch[i - 1];
        for (int g = bp + 1; g <= b; g++) starts[g] = i;
    }
    if (i == n - 1) {
        for (int g = b + 1; g <= G; g++) starts[g] = n;
    }
}

// countdown-cursor fill: reuses cnt (holds deg) as cursor via atomicSub
__global__ void fill_csr_kernel(const int* __restrict__ src, const int* __restrict__ dst,
                                const int* __restrict__ offs, int* __restrict__ cnt,
                                unsigned short* __restrict__ csr, int E) {
    int e = blockIdx.x * blockDim.x + threadIdx.x;
    if (e < E) {
        int d = dst[e];
        int p = atomicSub(&cnt[d], 1);  // returns old value in [1, deg]
        csr[offs[d] + p - 1] = (unsigned short)src[e];
    }
}

// all-layer W fp32 -> bf16 hi/lo planes (linear layout, single launch)
__global__ void wconv_kernel(const float* __restrict__ W1, const float* __restrict__ W2,
                             const float* __restrict__ W3, const float* __restrict__ W4,
                             short* __restrict__ Whi, short* __restrict__ Wlo) {
    int i = blockIdx.x * blockDim.x + threadIdx.x;
    const int n1 = HID * F_IN, nk = HID * HID;
    float v;
    if (i < n1) v = W1[i];
    else if (i < n1 + nk) v = W2[i - n1];
    else if (i < n1 + 2 * nk) v = W3[i - n1 - nk];
    else if (i < n1 + 3 * nk) v = W4[i - n1 - 2 * nk];
    else return;
    short h, l;
    split_bf16(v, h, l);
    Whi[i] = h;
    Wlo[i] = l;
}

// -------- XCD-affine chunked aggregation + fused bf16-pair conversion --------
// out_i = dis_i * (dis_i*H_i + sum_j dis_j*H_j), linear hi/lo planes.
// R6-proven config: 1 wave = 1 node x 64 cols, 8-deep pipeline, 85 us.
template <int F, int CHUNKS>
__global__ __launch_bounds__(64) void agg_chunk_kernel(
    const float* __restrict__ H, const float* __restrict__ dis,
    const int* __restrict__ offs, const unsigned short* __restrict__ csr,
    short* __restrict__ Ahi, short* __restrict__ Alo, int n) {
    int blk = blockIdx.x;
    int i = blk / CHUNKS;
    int chunk = blk % CHUNKS;
    int col = chunk * 64 + threadIdx.x;
    const float* Hc = H + col;

    float di = dis[i];
    float a = di * Hc[(size_t)i * F];
    int e = offs[i], e1 = offs[i + 1];
    for (; e + 8 <= e1; e += 8) {
        int j0 = csr[e],     j1 = csr[e + 1], j2 = csr[e + 2], j3 = csr[e + 3];
        int j4 = csr[e + 4], j5 = csr[e + 5], j6 = csr[e + 6], j7 = csr[e + 7];
        float d0 = dis[j0], d1 = dis[j1], d2 = dis[j2], d3 = dis[j3];
        float d4 = dis[j4], d5 = dis[j5], d6 = dis[j6], d7 = dis[j7];
        float r0 = Hc[(size_t)j0 * F], r1 = Hc[(size_t)j1 * F];
        float r2 = Hc[(size_t)j2 * F], r3 = Hc[(size_t)j3 * F];
        float r4 = Hc[(size_t)j4 * F], r5 = Hc[(size_t)j5 * F];
        float r6 = Hc[(size_t)j6 * F], r7 = Hc[(size_t)j7 * F];
        a += d0 * r0 + d1 * r1 + d2 * r2 + d3 * r3;
        a += d4 * r4 + d5 * r5 + d6 * r6 + d7 * r7;
    }
    for (; e < e1; e++) {
        int j = csr[e];
        a += dis[j] * Hc[(size_t)j * F];
    }
    a *= di;
    short h, l;
    split_bf16(a, h, l);
    Ahi[(size_t)i * F + col] = h;
    Alo[(size_t)i * F + col] = l;
}

// -------- fat-wave barrier-free split-bf16 MFMA GEMM (linear operands) --------
// C[M,512] = A[M,K] @ W[512,K]^T + bias; 3 products hi*hi + hi*lo + lo*hi.
// 1 wave per block; wave tile 64m x 128n (4 m-sub x 8 n-sub), single-buffered
// operand frags loaded straight from LINEAR A/W (lane pattern touches 16 fully-
// consumed 64B lines per frag). No LDS, no barriers. acc 128 + frags 96 VGPR.
// XCD-affine decode: all 4 n-blocks of an m-tile run consecutively on ONE XCD,
// so the A band is fetched from L3 once and L2-hits for the other 3 readers.
template <int KT>
__global__ __launch_bounds__(64, 2) void gemm_flat_kernel(
    const short* __restrict__ Ahi, const short* __restrict__ Alo,
    const short* __restrict__ Whi, const short* __restrict__ Wlo,
    const float* __restrict__ bias, float* __restrict__ C,
    int M, int MT) {
    const int K = KT * 32;
    int blk = blockIdx.x;
    int xcd = blk & 7;
    int q = blk >> 3;
    int nt = q & 3;
    int mt = xcd + 8 * (q >> 2);
    if (mt >= MT) return;
    int m0 = mt * 64, n0 = nt * 128;

    int l = threadIdx.x;
    int lrow = l & 15, lq = l >> 4;

    // lane base offsets (in shorts)
    size_t abase = (size_t)(m0 + lrow) * K + lq * 8;
    size_t wbase = (size_t)(n0 + lrow) * K + lq * 8;

    f32x4 acc[4][8];
    #pragma unroll
    for (int i = 0; i < 4; i++)
        #pragma unroll
        for (int j = 0; j < 8; j++) acc[i][j] = (f32x4){0.f, 0.f, 0.f, 0.f};

    for (int kt = 0; kt < KT; kt++) {
        size_t ko = (size_t)kt * 32;
        bf16x8 ah[4], al[4], wh[8], wl[8];
        #pragma unroll
        for (int i = 0; i < 4; i++) {
            size_t ad = abase + (size_t)i * 16 * K + ko;
            ah[i] = *(const bf16x8*)&Ahi[ad];
            al[i] = *(const bf16x8*)&Alo[ad];
        }
        #pragma unroll
        for (int j = 0; j < 8; j++) {
            size_t wd = wbase + (size_t)j * 16 * K + ko;
            wh[j] = *(const bf16x8*)&Whi[wd];
            wl[j] = *(const bf16x8*)&Wlo[wd];
        }
        #pragma unroll
        for (int i = 0; i < 4; i++)
            #pragma unroll
            for (int j = 0; j < 8; j++) {
                acc[i][j] = __builtin_amdgcn_mfma_f32_16x16x32_bf16(ah[i], wh[j], acc[i][j], 0, 0, 0);
                acc[i][j] = __builtin_amdgcn_mfma_f32_16x16x32_bf16(ah[i], wl[j], acc[i][j], 0, 0, 0);
                acc[i][j] = __builtin_amdgcn_mfma_f32_16x16x32_bf16(al[i], wh[j], acc[i][j], 0, 0, 0);
            }
    }

    // epilogue: C/D layout col=lane&15, row=(lane>>4)*4+reg
    #pragma unroll
    for (int j = 0; j < 8; j++) {
        int col = n0 + j * 16 + lrow;
        float bv = bias[col];
        #pragma unroll
        for (int i = 0; i < 4; i++) {
            int mrow = m0 + i * 16 + lq * 4;
            #pragma unroll
            for (int rr = 0; rr < 4; rr++) {
                int mm = mrow + rr;
                if (mm < M) C[(size_t)mm * HID + col] = acc[i][j][rr] + bv;
            }
        }
    }
}

// ---------------- pooling: per-layer segment max + fraction positive ----------------
__global__ __launch_bounds__(64) void pool_kernel(
    const float* __restrict__ H, const int* __restrict__ starts,
    float* __restrict__ out, int layer) {
    int g = blockIdx.x;
    int c = blockIdx.y * 64 + threadIdx.x;   // 0..511
    int s = starts[g], e = starts[g + 1];
    float mx = -INFINITY;
    int pos = 0;
    #pragma unroll 4
    for (int n = s; n < e; n++) {
        float v = H[(size_t)n * HID + c];
        mx = fmaxf(mx, v);
        pos += (v > 0.0f) ? 1 : 0;
    }
    float cntf = fmaxf((float)(e - s), 1.0f);
    out[(size_t)g * (8 * HID) + layer * HID + c] = mx;
    out[(size_t)g * (8 * HID) + 4 * HID + layer * HID + c] = (float)pos / cntf;
}

// ---------------- launcher ----------------
extern "C" void kernel_launch(void* const* d_in, const int* in_sizes, int n_in,
                              void* d_out, int out_size, void* d_ws, size_t ws_size,
                              hipStream_t stream) {
    const float* x     = (const float*)d_in[0];
    const int*   eidx  = (const int*)d_in[1];
    const int*   batch = (const int*)d_in[2];
    const float* W1 = (const float*)d_in[5];
    const float* b1 = (const float*)d_in[6];
    const float* W2 = (const float*)d_in[7];
    const float* b2 = (const float*)d_in[8];
    const float* W3 = (const float*)d_in[9];
    const float* b3 = (const float*)d_in[10];
    const float* W4 = (const float*)d_in[11];
    const float* b4 = (const float*)d_in[12];
    float* out = (float*)d_out;

    const int N = in_sizes[0] / F_IN;   // 20000
    const int E = in_sizes[1] / 2;      // 320000
    const int G = out_size / (8 * HID); // 256

    const int* src = eidx;
    const int* dst = eidx + E;

    // workspace layout (16B-aligned segments first).
    // A planes padded by 64 rows: last m-tile (rows 19968..20031) reads past
    // row N-1; pad keeps those loads inside the allocation (values guarded at C-store).
    const int NP = N + 64;
    const size_t nW = (size_t)HID * F_IN + 3 * (size_t)HID * HID;
    char* w = (char*)d_ws;
    short* Ahi = (short*)w; w += (size_t)NP * HID * sizeof(short);
    short* Alo = (short*)w; w += (size_t)NP * HID * sizeof(short);
    float* H   = (float*)w; w += (size_t)N * HID * sizeof(float);
    short* Whi = (short*)w; w += nW * sizeof(short);
    short* Wlo = (short*)w; w += nW * sizeof(short);
    int* offs  = (int*)w;   w += (size_t)(N + 4) * sizeof(int);
    unsigned short* csr = (unsigned short*)w; w += (size_t)E * sizeof(unsigned short);
    int* cnt   = (int*)w;   w += (size_t)N * sizeof(int);
    float* dis = (float*)w; w += (size_t)N * sizeof(float);
    int* starts = (int*)w;  w += (size_t)(G + 1) * sizeof(int);

    const size_t wo1 = 0;
    const size_t wo2 = (size_t)HID * F_IN;
    const size_t wo3 = wo2 + (size_t)HID * HID;
    const size_t wo4 = wo3 + (size_t)HID * HID;

    const int TB = 256;
    // ---- preprocessing: CSR over dst, dis, graph boundaries, W planes ----
    zero_kernel<<<(N + TB - 1) / TB, TB, 0, stream>>>(cnt, N);
    count_in_kernel<<<(E + TB - 1) / TB, TB, 0, stream>>>(dst, cnt, E);
    scan_kernel<<<1, 1024, 0, stream>>>(cnt, offs, N);
    dis_starts_kernel<<<(N + TB - 1) / TB, TB, 0, stream>>>(offs, dis, batch, starts, N, G);
    fill_csr_kernel<<<(E + TB - 1) / TB, TB, 0, stream>>>(src, dst, offs, cnt, csr, E);
    wconv_kernel<<<((int)nW + TB - 1) / TB, TB, 0, stream>>>(W1, W2, W3, W4, Whi, Wlo);

    const int MT = (N + 63) / 64;               // 313 m-tiles of 64 rows
    const int MT8 = (MT + 7) / 8;               // m-tiles per XCD band
    const int gemm_blocks = 8 * MT8 * 4;        // xcd-affine 1D grid (some idle-guarded)
    dim3 pool_grid(G, HID / 64);

    // ---- layer 1: h1 = (A x) @ W1^T + b1 ----
    agg_chunk_kernel<F_IN, 2><<<N * 2, 64, 0, stream>>>(x, dis, offs, csr, Ahi, Alo, N);
    gemm_flat_kernel<4><<<gemm_blocks, 64, 0, stream>>>(Ahi, Alo, Whi + wo1, Wlo + wo1, b1, H, N, MT);
    pool_kernel<<<pool_grid, 64, 0, stream>>>(H, starts, out, 0);

    // ---- layers 2..4 ----
    const size_t wos[3] = {wo2, wo3, wo4};
    const float* bs_[3] = {b2, b3, b4};
    for (int ll = 0; ll < 3; ll++) {
        agg_chunk_kernel<HID, 8><<<N * 8, 64, 0, stream>>>(H, dis, offs, csr, Ahi, Alo, N);
        gemm_flat_kernel<16><<<gemm_blocks, 64, 0, stream>>>(Ahi, Alo, Whi + wos[ll], Wlo + wos[ll], bs_[ll], H, N, MT);
        pool_kernel<<<pool_grid, 64, 0, stream>>>(H, starts, out, ll + 1);
    }
}

// Round 11
// 717.538 us; speedup vs baseline: 1.0409x; 1.0409x over previous
//
#include <hip/hip_runtime.h>
#include <cfloat>
#include <cmath>

#define F_IN 128
#define HID 512

typedef short bf16x8 __attribute__((ext_vector_type(8)));
typedef float f32x4 __attribute__((ext_vector_type(4)));

// ---- bf16 split helpers (RNE) ----
__device__ static inline void split_bf16(float v, short& hi, short& lo) {
    unsigned u = __float_as_uint(v);
    unsigned r = u + 0x7FFF + ((u >> 16) & 1);
    hi = (short)(r >> 16);
    float hf = __uint_as_float(((unsigned)(unsigned short)hi) << 16);
    float res = v - hf;
    unsigned u2 = __float_as_uint(res);
    unsigned r2 = u2 + 0x7FFF + ((u2 >> 16) & 1);
    lo = (short)(r2 >> 16);
}

// ---------------- small utility kernels ----------------

__global__ void zero_kernel(int* __restrict__ a, int n) {
    int i = blockIdx.x * blockDim.x + threadIdx.x;
    if (i < n) a[i] = 0;
}

__global__ void count_in_kernel(const int* __restrict__ dst, int* __restrict__ cnt, int E) {
    int e = blockIdx.x * blockDim.x + threadIdx.x;
    if (e < E) atomicAdd(&cnt[dst[e]], 1);
}

// single-block scan (exclusive prefix sum) + dis + graph-boundary starts
__global__ void scan_dis_starts_kernel(const int* __restrict__ cnt, int* __restrict__ offs,
                                       float* __restrict__ dis, const int* __restrict__ batch,
                                       int* __restrict__ starts, int n, int G) {
    __shared__ int buf[1024];
    __shared__ int carry_s;
    if (threadIdx.x == 0) carry_s = 0;
    __syncthreads();
    for (int base = 0; base < n; base += 1024) {
        int i = base + threadIdx.x;
        int v = (i < n) ? cnt[i] : 0;
        buf[threadIdx.x] = v;
        __syncthreads();
        for (int s = 1; s < 1024; s <<= 1) {
            int t = (threadIdx.x >= s) ? buf[threadIdx.x - s] : 0;
            __syncthreads();
            buf[threadIdx.x] += t;
            __syncthreads();
        }
        int total = buf[1023];
        if (i < n) offs[i] = carry_s + buf[threadIdx.x] - v;
        __syncthreads();
        if (threadIdx.x == 0) carry_s += total;
        __syncthreads();
    }
    if (threadIdx.x == 0) offs[n] = carry_s;
    __syncthreads();
    // dis + starts (offs fully written by this block)
    for (int i = threadIdx.x; i < n; i += 1024) {
        dis[i] = rsqrtf((float)(offs[i + 1] - offs[i] + 1));  // +1 self-loop
        int b = batch[i];
        if (i == 0) {
            for (int g = 0; g <= b; g++) starts[g] = 0;
        } else {
            int bp = batch[i - 1];
            for (int g = bp + 1; g <= b; g++) starts[g] = i;
        }
        if (i == n - 1) {
            for (int g = b + 1; g <= G; g++) starts[g] = n;
        }
    }
}

// countdown-cursor fill: reuses cnt (holds deg) as cursor via atomicSub
__global__ void fill_csr_kernel(const int* __restrict__ src, const int* __restrict__ dst,
                                const int* __restrict__ offs, int* __restrict__ cnt,
                                unsigned short* __restrict__ csr, int E) {
    int e = blockIdx.x * blockDim.x + threadIdx.x;
    if (e < E) {
        int d = dst[e];
        int p = atomicSub(&cnt[d], 1);  // returns old value in [1, deg]
        csr[offs[d] + p - 1] = (unsigned short)src[e];
    }
}

// all-layer W fp32 -> bf16 hi/lo planes (linear layout, single launch)
__global__ void wconv_kernel(const float* __restrict__ W1, const float* __restrict__ W2,
                             const float* __restrict__ W3, const float* __restrict__ W4,
                             short* __restrict__ Whi, short* __restrict__ Wlo) {
    int i = blockIdx.x * blockDim.x + threadIdx.x;
    const int n1 = HID * F_IN, nk = HID * HID;
    float v;
    if (i < n1) v = W1[i];
    else if (i < n1 + nk) v = W2[i - n1];
    else if (i < n1 + 2 * nk) v = W3[i - n1 - nk];
    else if (i < n1 + 3 * nk) v = W4[i - n1 - 2 * nk];
    else return;
    short h, l;
    split_bf16(v, h, l);
    Whi[i] = h;
    Wlo[i] = l;
}

// -------- agg (F=128, layer 1): R6-proven scalar-gather config, untouched --------
template <int F, int CHUNKS>
__global__ __launch_bounds__(64) void agg_chunk_kernel(
    const float* __restrict__ H, const float* __restrict__ dis,
    const int* __restrict__ offs, const unsigned short* __restrict__ csr,
    short* __restrict__ Ahi, short* __restrict__ Alo, int n) {
    int blk = blockIdx.x;
    int i = blk / CHUNKS;
    int chunk = blk % CHUNKS;
    int col = chunk * 64 + threadIdx.x;
    const float* Hc = H + col;

    float di = dis[i];
    float a = di * Hc[(size_t)i * F];
    int e = offs[i], e1 = offs[i + 1];
    for (; e + 8 <= e1; e += 8) {
        int j0 = csr[e],     j1 = csr[e + 1], j2 = csr[e + 2], j3 = csr[e + 3];
        int j4 = csr[e + 4], j5 = csr[e + 5], j6 = csr[e + 6], j7 = csr[e + 7];
        float d0 = dis[j0], d1 = dis[j1], d2 = dis[j2], d3 = dis[j3];
        float d4 = dis[j4], d5 = dis[j5], d6 = dis[j6], d7 = dis[j7];
        float r0 = Hc[(size_t)j0 * F], r1 = Hc[(size_t)j1 * F];
        float r2 = Hc[(size_t)j2 * F], r3 = Hc[(size_t)j3 * F];
        float r4 = Hc[(size_t)j4 * F], r5 = Hc[(size_t)j5 * F];
        float r6 = Hc[(size_t)j6 * F], r7 = Hc[(size_t)j7 * F];
        a += d0 * r0 + d1 * r1 + d2 * r2 + d3 * r3;
        a += d4 * r4 + d5 * r5 + d6 * r6 + d7 * r7;
    }
    for (; e < e1; e++) {
        int j = csr[e];
        a += dis[j] * Hc[(size_t)j * F];
    }
    a *= di;
    short h, l;
    split_bf16(a, h, l);
    Ahi[(size_t)i * F + col] = h;
    Alo[(size_t)i * F + col] = l;
}

// -------- agg (F=512): float2 gather, 128-col chunks — HALVED VMEM instr count --------
// Same 1-node/wave, 8-deep pipeline, same edge order (sums bit-identical to R6).
// 64 lanes x 8B = 512 B per gather instruction (vs 256 B), blocks halved to N*4.
// XCD slice: chunk c -> XCD c (even nodes) / c+4 (odd nodes) = 10000 x 128 x 4B = 5.1 MB.
template <int F, int CHUNKS>
__global__ __launch_bounds__(64) void agg_chunk2_kernel(
    const float* __restrict__ H, const float* __restrict__ dis,
    const int* __restrict__ offs, const unsigned short* __restrict__ csr,
    short* __restrict__ Ahi, short* __restrict__ Alo, int n) {
    int blk = blockIdx.x;
    int i = blk / CHUNKS;
    int chunk = blk % CHUNKS;
    int col = chunk * 128 + threadIdx.x * 2;
    const float2* Hc = (const float2*)(H + col);
    const int FS = F / 2;   // row stride in float2

    float di = dis[i];
    float2 h = Hc[(size_t)i * FS];
    float ax = di * h.x, ay = di * h.y;
    int e = offs[i], e1 = offs[i + 1];
    for (; e + 8 <= e1; e += 8) {
        int j0 = csr[e],     j1 = csr[e + 1], j2 = csr[e + 2], j3 = csr[e + 3];
        int j4 = csr[e + 4], j5 = csr[e + 5], j6 = csr[e + 6], j7 = csr[e + 7];
        float d0 = dis[j0], d1 = dis[j1], d2 = dis[j2], d3 = dis[j3];
        float d4 = dis[j4], d5 = dis[j5], d6 = dis[j6], d7 = dis[j7];
        float2 r0 = Hc[(size_t)j0 * FS], r1 = Hc[(size_t)j1 * FS];
        float2 r2 = Hc[(size_t)j2 * FS], r3 = Hc[(size_t)j3 * FS];
        float2 r4 = Hc[(size_t)j4 * FS], r5 = Hc[(size_t)j5 * FS];
        float2 r6 = Hc[(size_t)j6 * FS], r7 = Hc[(size_t)j7 * FS];
        ax += d0 * r0.x + d1 * r1.x + d2 * r2.x + d3 * r3.x;
        ax += d4 * r4.x + d5 * r5.x + d6 * r6.x + d7 * r7.x;
        ay += d0 * r0.y + d1 * r1.y + d2 * r2.y + d3 * r3.y;
        ay += d4 * r4.y + d5 * r5.y + d6 * r6.y + d7 * r7.y;
    }
    for (; e < e1; e++) {
        int j = csr[e];
        float d = dis[j];
        float2 r = Hc[(size_t)j * FS];
        ax += d * r.x;
        ay += d * r.y;
    }
    ax *= di; ay *= di;
    short hx, lx, hy, ly;
    split_bf16(ax, hx, lx);
    split_bf16(ay, hy, ly);
    *(short2*)&Ahi[(size_t)i * F + col] = make_short2(hx, hy);
    *(short2*)&Alo[(size_t)i * F + col] = make_short2(lx, ly);
}

// -------- fat-wave barrier-free split-bf16 MFMA GEMM (linear operands, R10-proven) ----
template <int KT>
__global__ __launch_bounds__(64, 2) void gemm_flat_kernel(
    const short* __restrict__ Ahi, const short* __restrict__ Alo,
    const short* __restrict__ Whi, const short* __restrict__ Wlo,
    const float* __restrict__ bias, float* __restrict__ C,
    int M, int MT) {
    const int K = KT * 32;
    int blk = blockIdx.x;
    int xcd = blk & 7;
    int q = blk >> 3;
    int nt = q & 3;
    int mt = xcd + 8 * (q >> 2);
    if (mt >= MT) return;
    int m0 = mt * 64, n0 = nt * 128;

    int l = threadIdx.x;
    int lrow = l & 15, lq = l >> 4;

    size_t abase = (size_t)(m0 + lrow) * K + lq * 8;
    size_t wbase = (size_t)(n0 + lrow) * K + lq * 8;

    f32x4 acc[4][8];
    #pragma unroll
    for (int i = 0; i < 4; i++)
        #pragma unroll
        for (int j = 0; j < 8; j++) acc[i][j] = (f32x4){0.f, 0.f, 0.f, 0.f};

    for (int kt = 0; kt < KT; kt++) {
        size_t ko = (size_t)kt * 32;
        bf16x8 ah[4], al[4], wh[8], wl[8];
        #pragma unroll
        for (int i = 0; i < 4; i++) {
            size_t ad = abase + (size_t)i * 16 * K + ko;
            ah[i] = *(const bf16x8*)&Ahi[ad];
            al[i] = *(const bf16x8*)&Alo[ad];
        }
        #pragma unroll
        for (int j = 0; j < 8; j++) {
            size_t wd = wbase + (size_t)j * 16 * K + ko;
            wh[j] = *(const bf16x8*)&Whi[wd];
            wl[j] = *(const bf16x8*)&Wlo[wd];
        }
        #pragma unroll
        for (int i = 0; i < 4; i++)
            #pragma unroll
            for (int j = 0; j < 8; j++) {
                acc[i][j] = __builtin_amdgcn_mfma_f32_16x16x32_bf16(ah[i], wh[j], acc[i][j], 0, 0, 0);
                acc[i][j] = __builtin_amdgcn_mfma_f32_16x16x32_bf16(ah[i], wl[j], acc[i][j], 0, 0, 0);
                acc[i][j] = __builtin_amdgcn_mfma_f32_16x16x32_bf16(al[i], wh[j], acc[i][j], 0, 0, 0);
            }
    }

    // epilogue: C/D layout col=lane&15, row=(lane>>4)*4+reg
    #pragma unroll
    for (int j = 0; j < 8; j++) {
        int col = n0 + j * 16 + lrow;
        float bv = bias[col];
        #pragma unroll
        for (int i = 0; i < 4; i++) {
            int mrow = m0 + i * 16 + lq * 4;
            #pragma unroll
            for (int rr = 0; rr < 4; rr++) {
                int mm = mrow + rr;
                if (mm < M) C[(size_t)mm * HID + col] = acc[i][j][rr] + bv;
            }
        }
    }
}

// ---------------- pooling: per-layer segment max + fraction positive ----------------
__global__ __launch_bounds__(64) void pool_kernel(
    const float* __restrict__ H, const int* __restrict__ starts,
    float* __restrict__ out, int layer) {
    int g = blockIdx.x;
    int c = blockIdx.y * 64 + threadIdx.x;   // 0..511
    int s = starts[g], e = starts[g + 1];
    float mx = -INFINITY;
    int pos = 0;
    #pragma unroll 4
    for (int n = s; n < e; n++) {
        float v = H[(size_t)n * HID + c];
        mx = fmaxf(mx, v);
        pos += (v > 0.0f) ? 1 : 0;
    }
    float cntf = fmaxf((float)(e - s), 1.0f);
    out[(size_t)g * (8 * HID) + layer * HID + c] = mx;
    out[(size_t)g * (8 * HID) + 4 * HID + layer * HID + c] = (float)pos / cntf;
}

// ---------------- launcher ----------------
extern "C" void kernel_launch(void* const* d_in, const int* in_sizes, int n_in,
                              void* d_out, int out_size, void* d_ws, size_t ws_size,
                              hipStream_t stream) {
    const float* x     = (const float*)d_in[0];
    const int*   eidx  = (const int*)d_in[1];
    const int*   batch = (const int*)d_in[2];
    const float* W1 = (const float*)d_in[5];
    const float* b1 = (const float*)d_in[6];
    const float* W2 = (const float*)d_in[7];
    const float* b2 = (const float*)d_in[8];
    const float* W3 = (const float*)d_in[9];
    const float* b3 = (const float*)d_in[10];
    const float* W4 = (const float*)d_in[11];
    const float* b4 = (const float*)d_in[12];
    float* out = (float*)d_out;

    const int N = in_sizes[0] / F_IN;   // 20000
    const int E = in_sizes[1] / 2;      // 320000
    const int G = out_size / (8 * HID); // 256

    const int* src = eidx;
    const int* dst = eidx + E;

    // workspace layout (16B-aligned segments first).
    // A planes padded by 64 rows (last m-tile over-read; values guarded at C-store).
    const int NP = N + 64;
    const size_t nW = (size_t)HID * F_IN + 3 * (size_t)HID * HID;
    char* w = (char*)d_ws;
    short* Ahi = (short*)w; w += (size_t)NP * HID * sizeof(short);
    short* Alo = (short*)w; w += (size_t)NP * HID * sizeof(short);
    float* H   = (float*)w; w += (size_t)N * HID * sizeof(float);
    short* Whi = (short*)w; w += nW * sizeof(short);
    short* Wlo = (short*)w; w += nW * sizeof(short);
    int* offs  = (int*)w;   w += (size_t)(N + 4) * sizeof(int);
    unsigned short* csr = (unsigned short*)w; w += (size_t)E * sizeof(unsigned short);
    int* cnt   = (int*)w;   w += (size_t)N * sizeof(int);
    float* dis = (float*)w; w += (size_t)N * sizeof(float);
    int* starts = (int*)w;  w += (size_t)(G + 1) * sizeof(int);

    const size_t wo1 = 0;
    const size_t wo2 = (size_t)HID * F_IN;
    const size_t wo3 = wo2 + (size_t)HID * HID;
    const size_t wo4 = wo3 + (size_t)HID * HID;

    const int TB = 256;
    // ---- preprocessing: CSR over dst, dis, graph boundaries, W planes ----
    zero_kernel<<<(N + TB - 1) / TB, TB, 0, stream>>>(cnt, N);
    count_in_kernel<<<(E + TB - 1) / TB, TB, 0, stream>>>(dst, cnt, E);
    scan_dis_starts_kernel<<<1, 1024, 0, stream>>>(cnt, offs, dis, batch, starts, N, G);
    fill_csr_kernel<<<(E + TB - 1) / TB, TB, 0, stream>>>(src, dst, offs, cnt, csr, E);
    wconv_kernel<<<((int)nW + TB - 1) / TB, TB, 0, stream>>>(W1, W2, W3, W4, Whi, Wlo);

    const int MT = (N + 63) / 64;               // 313 m-tiles of 64 rows
    const int MT8 = (MT + 7) / 8;               // m-tiles per XCD band
    const int gemm_blocks = 8 * MT8 * 4;        // xcd-affine 1D grid (some idle-guarded)
    dim3 pool_grid(G, HID / 64);

    // ---- layer 1: h1 = (A x) @ W1^T + b1 ----
    agg_chunk_kernel<F_IN, 2><<<N * 2, 64, 0, stream>>>(x, dis, offs, csr, Ahi, Alo, N);
    gemm_flat_kernel<4><<<gemm_blocks, 64, 0, stream>>>(Ahi, Alo, Whi + wo1, Wlo + wo1, b1, H, N, MT);
    pool_kernel<<<pool_grid, 64, 0, stream>>>(H, starts, out, 0);

    // ---- layers 2..4 ----
    const size_t wos[3] = {wo2, wo3, wo4};
    const float* bs_[3] = {b2, b3, b4};
    for (int ll = 0; ll < 3; ll++) {
        agg_chunk2_kernel<HID, 4><<<N * 4, 64, 0, stream>>>(H, dis, offs, csr, Ahi, Alo, N);
        gemm_flat_kernel<16><<<gemm_blocks, 64, 0, stream>>>(Ahi, Alo, Whi + wos[ll], Wlo + wos[ll], bs_[ll], H, N, MT);
        pool_kernel<<<pool_grid, 64, 0, stream>>>(H, starts, out, ll + 1);
    }
}